// Round 19
// baseline (406.809 us; speedup 1.0000x reference)
//
#include <hip/hip_runtime.h>
#include <hip/hip_bf16.h>

#define NN 50000
#define EE 600000
#define HH 128
#define OUTD 32
#define RR 64
#define BB 16
#define KK 2048   // BB*HH
#define SC_B ((NN + 1023) / 1024)  // 49 scan chunks
#define N_CONVW ((HH + OUTD) * KK)
#define N_EMB   (NN * HH / 2)
#define TILEB   262144   // 64 rows x 4KB = 256KB per A tile (K-major chunks)

typedef short s16x8 __attribute__((ext_vector_type(8)));
typedef float f32x4 __attribute__((ext_vector_type(4)));
typedef float f32x2 __attribute__((ext_vector_type(2)));
typedef unsigned short ushort_t;
typedef unsigned int uint_t;

__device__ inline ushort_t f_to_bf16(float f){
    __hip_bfloat16 h = __float2bfloat16(f);
    return *reinterpret_cast<ushort_t*>(&h);
}
__device__ inline uint_t pack_bf16x2(float a, float b){
    return (uint_t)f_to_bf16(a) | ((uint_t)f_to_bf16(b) << 16);
}

__global__ void hist_kernel(const int* __restrict__ dst, int* counts){
    int e = blockIdx.x*256 + threadIdx.x;
    if (e < EE) atomicAdd(&counts[dst[e]], 1);
}

// ---- hierarchical scan: chunk totals -> scan totals -> final ----
__global__ void scan_part(const int* __restrict__ counts, int* __restrict__ tot){
    int b = blockIdx.x, t = threadIdx.x;
    int i0 = b*1024 + t*4;
    int s = 0;
    if (i0 + 3 < NN){
        int4 v = *reinterpret_cast<const int4*>(&counts[i0]);
        s = v.x + v.y + v.z + v.w;
    } else {
        for (int j = 0; j < 4; j++) if (i0 + j < NN) s += counts[i0 + j];
    }
    #pragma unroll
    for (int off = 32; off; off >>= 1) s += __shfl_xor(s, off, 64);
    __shared__ int ws[4];
    if ((t & 63) == 0) ws[t >> 6] = s;
    __syncthreads();
    if (t == 0) tot[b] = ws[0] + ws[1] + ws[2] + ws[3];
}

__global__ void scan_tot(int* tot){  // 1 block, 64 threads (SC_B <= 64)
    int t = threadIdx.x;
    int v = (t < SC_B) ? tot[t] : 0;
    int x = v;
    #pragma unroll
    for (int off = 1; off < 64; off <<= 1){
        int y = __shfl_up(x, off, 64);
        if (t >= off) x += y;
    }
    if (t < SC_B) tot[t] = x - v;  // exclusive base per chunk
}

__global__ void scan_final(const int* __restrict__ counts, const int* __restrict__ tot,
                           int* __restrict__ offsets, int* __restrict__ cursor){
    int b = blockIdx.x, t = threadIdx.x, lane = t & 63, wv = t >> 6;
    int i0 = b*1024 + t*4;
    int v[4]; int s = 0;
    #pragma unroll
    for (int j = 0; j < 4; j++){ v[j] = (i0 + j < NN) ? counts[i0 + j] : 0; s += v[j]; }
    int x = s;
    #pragma unroll
    for (int off = 1; off < 64; off <<= 1){
        int y = __shfl_up(x, off, 64);
        if (lane >= off) x += y;
    }
    __shared__ int ws[4];
    if (lane == 63) ws[wv] = x;
    __syncthreads();
    int pre = tot[b];
    for (int i = 0; i < wv; i++) pre += ws[i];
    int run = pre + x - s;  // exclusive start of this thread's 4 elems
    #pragma unroll
    for (int j = 0; j < 4; j++){
        if (i0 + j < NN){
            cursor[i0 + j] = run;
            offsets[i0 + j + 1] = run + v[j];
        }
        run += v[j];
    }
    if (b == 0 && t == 0) offsets[0] = 0;
}

// scatter dst-sorted edge payload: msrc[r] = src row, netn[r] = norm_bits|etype
__global__ void scatter_kernel(const int* __restrict__ dst, const int* __restrict__ src,
                               const int* __restrict__ etype, const float* __restrict__ norm,
                               int* cursor, int* __restrict__ msrc, int* __restrict__ netn){
    int e = blockIdx.x*256 + threadIdx.x;
    if (e >= EE) return;
    int d = dst[e];
    int r = atomicAdd(&cursor[d], 1);
    msrc[r] = src[e];
    netn[r] = (__float_as_int(norm[e]) & ~63) | etype[e];
}

// fused prologue: Wt1/Wt2 -> plain K-major tiled bf16; emb -> bf16.
// Wt layout: chunk kc = k>>6; byte addr = kc*(ROWS*128) + o*128 + (k&63)*2
__global__ void prep_kernel(const float* __restrict__ V1, const float* __restrict__ V2,
                            const float* __restrict__ emb,
                            ushort_t* __restrict__ Wt1, ushort_t* __restrict__ Wt2,
                            ushort_t* __restrict__ xb){
    int i = blockIdx.x*256 + threadIdx.x;
    if (i < HH*KK){
        int o = i / KK, k = i % KK;
        size_t addr = (size_t)(k >> 6)*16384 + (size_t)o*128 + (k & 63)*2;
        *reinterpret_cast<ushort_t*>(reinterpret_cast<char*>(Wt1) + addr) =
            f_to_bf16(V1[(size_t)k*HH + o]);
    } else if (i < N_CONVW){
        int j = i - HH*KK;
        int o = j / KK, k = j % KK;
        size_t addr = (size_t)(k >> 6)*4096 + (size_t)o*128 + (k & 63)*2;
        *reinterpret_cast<ushort_t*>(reinterpret_cast<char*>(Wt2) + addr) =
            f_to_bf16(V2[(size_t)k*OUTD + o]);
    } else if (i < N_CONVW + N_EMB){
        int j = i - N_CONVW;
        float2 f = *reinterpret_cast<const float2*>(emb + 2*(size_t)j);
        *reinterpret_cast<uint_t*>(xb + 2*(size_t)j) = pack_bf16x2(f.x, f.y);
    }
}

// Aggregate: 1 node per wave, 4 waves/block, no LDS/barriers. FMA loop
// unchanged. Store: plain K-major tiled agg (matches the GEMM's direct reads).
__global__ __launch_bounds__(256, 6) void agg_kernel(
    const ushort_t* __restrict__ xin, const int* __restrict__ msrc,
    const int* __restrict__ netn, const int* __restrict__ offsets,
    const float* __restrict__ comp, ushort_t* __restrict__ agg,
    int v0, int vc)
{
    int w = threadIdx.x >> 6, lane = threadIdx.x & 63;
    int v = v0 + blockIdx.x*4 + w;
    if (v >= v0 + vc) return;
    int p0 = offsets[v];
    int dd = offsets[v+1] - p0;
    const uint_t* xrow = reinterpret_cast<const uint_t*>(xin);  // row r at xrow + r*64

    f32x2 accA[8], accB[8];
    #pragma unroll
    for (int bp = 0; bp < 8; bp++){
        accA[bp].x = 0.f; accA[bp].y = 0.f;
        accB[bp].x = 0.f; accB[bp].y = 0.f;
    }

    for (int c0 = 0; c0 < dd; c0 += 64){
        int nc = min(64, dd - c0);
        int li = p0 + c0 + min(lane, nc - 1);
        int mp = msrc[li];      // lane e: src row of edge e
        int nr = netn[li];      // lane e: norm bits | etype
        uint_t xr[8];
        #pragma unroll
        for (int j = 0; j < 8; ++j){
            int sr = __builtin_amdgcn_readlane(mp, min(j, nc - 1));
            xr[j] = xrow[(size_t)sr*64 + lane];
        }
        for (int eb = 0; eb < nc; eb += 8){
            #pragma unroll
            for (int j = 0; j < 8; ++j){
                int e = eb + j;                       // uniform
                int ec = min(e, nc - 1);
                int nb = __builtin_amdgcn_readlane(nr, ec);
                int et = nb & 63;
                float nw = (e < nc) ? __int_as_float(nb & ~63) : 0.f;
                uint_t u = xr[j];
                f32x2 xs;
                xs.x = __uint_as_float(u << 16) * nw;         // feat 2*lane
                xs.y = __uint_as_float(u & 0xffff0000u) * nw; // feat 2*lane+1
                int en = e + 8;
                if (en < nc){                          // uniform branch: refill ring
                    int srn = __builtin_amdgcn_readlane(mp, en);
                    xr[j] = xrow[(size_t)srn*64 + lane];
                }
                const f32x2* cp = reinterpret_cast<const f32x2*>(comp + et*BB);
                #pragma unroll
                for (int bp = 0; bp < 8; bp++){
                    f32x2 c2 = cp[bp];   // {c[2bp], c[2bp+1]} consecutive SGPRs
                    asm("v_pk_fma_f32 %0, %1, %2, %0 op_sel:[0,0,0] op_sel_hi:[1,0,1]"
                        : "+v"(accA[bp]) : "s"(c2), "v"(xs));
                    asm("v_pk_fma_f32 %0, %1, %2, %0 op_sel:[0,1,0] op_sel_hi:[1,1,1]"
                        : "+v"(accB[bp]) : "s"(c2), "v"(xs));
                }
            }
        }
    }
    // store: k = b*128 + 2*lane -> chunk kc = b*2 + (lane>>5), byte (lane&31)*4
    {
        int idx = v - v0;
        char* tbase = reinterpret_cast<char*>(agg) + (size_t)(idx >> 6)*TILEB
                    + (size_t)(idx & 63)*128;
        int off = (lane & 31)*4;
        #pragma unroll
        for (int b = 0; b < BB; b++){
            uint_t pk;
            asm("v_cvt_pk_bf16_f32 %0, %1, %2"
                : "=v"(pk) : "v"(accA[b>>1][b&1]), "v"(accB[b>>1][b&1]));
            int kc = b*2 + (lane >> 5);
            *reinterpret_cast<uint_t*>(tbase + (size_t)kc*8192 + off) = pk;
        }
    }
}

// GEMM: C[m, o] = sum_k A[m,k] * Wt[o,k] (+bias, opt relu).
// Barrier-free / LDS-free: 1 wave per block; wave = 32 rows x (BN==128 ? 64 :
// 32) cols; MFMA operands loaded DIRECTLY global->VGPR from K-major tiled
// A and Wt (L2/L3-hot). Latency hidden by TLP (~16 independent waves/CU) +
// compiler s_waitcnt pipelining — the agg_kernel philosophy applied to GEMM.
template<int BN, bool RELU, bool OUT_BF16>
__global__ __launch_bounds__(64, 4) void gemm_kernel(
    const ushort_t* __restrict__ A, const ushort_t* __restrict__ Wt,
    const float* __restrict__ bias, void* __restrict__ yout, int vc)
{
    constexpr int CT = (BN == 128) ? 4 : 2;   // 16-col subtiles per wave
    constexpr int BROWB = BN * 128;           // bytes per Wt kc-chunk
    int lane = threadIdx.x;
    int lane15 = lane & 15;
    int bid = blockIdx.x;
    int rg, cb;
    if (BN == 128){ rg = bid >> 1; cb = (bid & 1)*64; }
    else          { rg = bid;      cb = 0; }
    int m0 = rg * 32;                          // chunk-local row base

    const char* Ab = reinterpret_cast<const char*>(A)
                   + (size_t)(m0 >> 6)*TILEB + (size_t)(m0 & 63)*128;
    const char* Bb = reinterpret_cast<const char*>(Wt);
    int loff = (lane >> 4)*16;                 // 16B granule within K=32 half

    f32x4 acc[2][CT];
    #pragma unroll
    for (int rt = 0; rt < 2; rt++)
        #pragma unroll
        for (int ct = 0; ct < CT; ct++)
            #pragma unroll
            for (int j = 0; j < 4; j++) acc[rt][ct][j] = 0.f;

    for (int kc = 0; kc < KK/64; ++kc){
        #pragma unroll
        for (int ks = 0; ks < 2; ++ks){
            s16x8 a0 = *reinterpret_cast<const s16x8*>(
                Ab + (size_t)(lane15)*128      + ks*64 + loff);
            s16x8 a1 = *reinterpret_cast<const s16x8*>(
                Ab + (size_t)(16 + lane15)*128 + ks*64 + loff);
            #pragma unroll
            for (int ct = 0; ct < CT; ct++){
                s16x8 b = *reinterpret_cast<const s16x8*>(
                    Bb + (size_t)(cb + ct*16 + lane15)*128 + ks*64 + loff);
                acc[0][ct] = __builtin_amdgcn_mfma_f32_16x16x32_bf16(a0, b, acc[0][ct], 0,0,0);
                acc[1][ct] = __builtin_amdgcn_mfma_f32_16x16x32_bf16(a1, b, acc[1][ct], 0,0,0);
            }
        }
        Ab += 8192;
        Bb += BROWB;
    }

    #pragma unroll
    for (int rt = 0; rt < 2; rt++){
        int rb = m0 + rt*16 + ((lane >> 4) << 2);
        #pragma unroll
        for (int ct = 0; ct < CT; ct++){
            int col = cb + ct*16 + lane15;
            float bv = bias[col];
            #pragma unroll
            for (int r = 0; r < 4; r++){
                int row = rb + r;
                if (row < vc){
                    float val = acc[rt][ct][r] + bv;
                    if (RELU) val = fmaxf(val, 0.f);
                    if (OUT_BF16)
                        reinterpret_cast<ushort_t*>(yout)[(size_t)row*BN + col] = f_to_bf16(val);
                    else
                        reinterpret_cast<float*>(yout)[(size_t)row*BN + col] = val;
                }
            }
        }
    }
}

extern "C" void kernel_launch(void* const* d_in, const int* in_sizes, int n_in,
                              void* d_out, int out_size, void* d_ws, size_t ws_size,
                              hipStream_t stream){
    const int*   src   = (const int*)d_in[0];
    const int*   dst   = (const int*)d_in[1];
    const int*   etype = (const int*)d_in[2];
    const float* norm  = (const float*)d_in[3];
    const float* emb   = (const float*)d_in[4];
    const float* V1    = (const float*)d_in[5];
    const float* comp1 = (const float*)d_in[6];
    const float* bias1 = (const float*)d_in[7];
    const float* V2    = (const float*)d_in[8];
    const float* comp2 = (const float*)d_in[9];
    const float* bias2 = (const float*)d_in[10];
    float* out = (float*)d_out;

    char* w = (char*)d_ws;
    auto alloc = [&](size_t bytes) -> char* {
        char* p = w; w += (bytes + 255) & ~(size_t)255; return p;
    };
    int*      offsets = (int*)alloc((NN + 1) * 4);
    int*      counts  = (int*)alloc(NN * 4);
    int*      cursor  = (int*)alloc(NN * 4);
    int*      tot     = (int*)alloc(SC_B * 4);
    int*      msrc    = (int*)alloc((size_t)EE * 4);
    int*      netn    = (int*)alloc((size_t)EE * 4);
    ushort_t* Wt1     = (ushort_t*)alloc((size_t)HH * KK * 2);
    ushort_t* Wt2     = (ushort_t*)alloc((size_t)OUTD * KK * 2);
    ushort_t* xb      = (ushort_t*)alloc((size_t)NN * HH * 2);
    ushort_t* h       = (ushort_t*)alloc((size_t)NN * HH * 2);
    size_t used  = (size_t)(w - (char*)d_ws);
    size_t avail = ws_size > used ? ws_size - used : 0;
    int maxTiles = (int)(avail / TILEB);
    int chunkN = maxTiles * 64;           // full 64-row tiles only
    if (chunkN < 64) chunkN = 64;
    if (chunkN > NN) chunkN = NN;
    ushort_t* agg = (ushort_t*)w;

    // CSR build + payload sort + weight/emb conversion
    hipMemsetAsync(counts, 0, NN * 4, stream);
    hist_kernel<<<(EE + 255)/256, 256, 0, stream>>>(dst, counts);
    scan_part<<<SC_B, 256, 0, stream>>>(counts, tot);
    scan_tot<<<1, 64, 0, stream>>>(tot);
    scan_final<<<SC_B, 256, 0, stream>>>(counts, tot, offsets, cursor);
    scatter_kernel<<<(EE + 255)/256, 256, 0, stream>>>(dst, src, etype, norm,
                                                       cursor, msrc, netn);
    prep_kernel<<<(N_CONVW + N_EMB + 255)/256, 256, 0, stream>>>(
        V1, V2, emb, Wt1, Wt2, xb);

    // layer 1: xb (bf16) -> h (bf16, relu)
    for (int v0 = 0; v0 < NN; v0 += chunkN){
        int vc = (NN - v0 < chunkN) ? (NN - v0) : chunkN;
        agg_kernel<<<(vc + 3)/4, 256, 0, stream>>>(
            xb, msrc, netn, offsets, comp1, agg, v0, vc);
        gemm_kernel<HH, true, true><<<((vc + 31)/32)*2, 64, 0, stream>>>(
            agg, Wt1, bias1, h + (size_t)v0 * HH, vc);
    }
    // layer 2: h (bf16) -> out (f32)
    for (int v0 = 0; v0 < NN; v0 += chunkN){
        int vc = (NN - v0 < chunkN) ? (NN - v0) : chunkN;
        agg_kernel<<<(vc + 3)/4, 256, 0, stream>>>(
            h, msrc, netn, offsets, comp2, agg, v0, vc);
        gemm_kernel<OUTD, false, false><<<(vc + 31)/32, 64, 0, stream>>>(
            agg, Wt2, bias2, out + (size_t)v0 * OUTD, vc);
    }
}